// Round 1
// 427.683 us; speedup vs baseline: 1.1356x; 1.1356x over previous
//
#include <hip/hip_runtime.h>
#include <hip/hip_fp16.h>
#include <math.h>

// FNOBlock via four-step FFT (4096 = 64 x 64), register-resident radix-8x8 FFTs.
// K1a: per (b,n2,ctile): FFT64 over n1 (8x8 in regs, LDS transpose), twiddle W4096^{n2 k1} -> ybuf
// K1b: per (b,k1,ctile): FFT64 over n2, keep k2 in {0..7,56..63} -> zbuf
// K2 : per (mode, o-half): 64x256x128 GEMM via MFMA (fp16 X in LDS, R split hi/lo fp16, fp32 acc)
// K3a: per (b,k1,ctile): pruned iFFT64 over k2 (16 nonzero), twiddle -> tbuf  (no LDS)
// K3b: per (b,n2,ctile): iFFT64 over k1, + residual v -> out

constexpr int BB = 32;
constexpr int CC = 256;
constexpr int MM = 512;

constexpr float PI2_4096 = 1.5339807878856412e-3f;   // 2*pi/4096
constexpr float PI2_512  = 1.2271846303085130e-2f;   // 2*pi/512
constexpr float PI2_64   = 9.8174770424681035e-2f;   // 2*pi/64
constexpr float PI_4     = 0.78539816339744831f;     // 2*pi/8

typedef _Float16 f16x8 __attribute__((ext_vector_type(8)));
typedef float f32x4 __attribute__((ext_vector_type(4)));

__device__ __forceinline__ float2 cadd(float2 a, float2 b){ return make_float2(a.x+b.x, a.y+b.y); }
__device__ __forceinline__ float2 csub(float2 a, float2 b){ return make_float2(a.x-b.x, a.y-b.y); }
__device__ __forceinline__ float2 cmulf(float2 a, float2 b){ return make_float2(a.x*b.x - a.y*b.y, a.x*b.y + a.y*b.x); }

// 8-pt DFT, natural order in/out. S=+1: forward (W8=e^{-2pi i/8}); S=-1: inverse (conj twiddles).
template<int S>
__device__ __forceinline__ void dif8(float2 x[8]) {
    const float R = 0.70710678118654752f;
    const float Sf = (float)S;
    float2 a0=cadd(x[0],x[4]), a1=cadd(x[1],x[5]), a2=cadd(x[2],x[6]), a3=cadd(x[3],x[7]);
    float2 d0=csub(x[0],x[4]), d1=csub(x[1],x[5]), d2=csub(x[2],x[6]), d3=csub(x[3],x[7]);
    float2 t5 = cmulf(d1, make_float2(R, -R*Sf));
    float2 t6 = make_float2(Sf*d2.y, -Sf*d2.x);                 // *(-iS)
    float2 t7 = cmulf(d3, make_float2(-R, -R*Sf));
    float2 b0=cadd(a0,a2), b1=cadd(a1,a3), b2=csub(a0,a2), e3=csub(a1,a3);
    float2 b3=make_float2(Sf*e3.y, -Sf*e3.x);
    float2 b4=cadd(d0,t6), b5=cadd(t5,t7), b6=csub(d0,t6), e7=csub(t5,t7);
    float2 b7=make_float2(Sf*e7.y, -Sf*e7.x);
    x[0]=cadd(b0,b1); x[4]=csub(b0,b1);
    x[2]=cadd(b2,b3); x[6]=csub(b2,b3);
    x[1]=cadd(b4,b5); x[5]=csub(b4,b5);
    x[3]=cadd(b6,b7); x[7]=csub(b6,b7);
}

// x[k] *= e^{i*ang*k}, k=1..7 (iterated powers)
__device__ __forceinline__ void twid7(float2 x[8], float ang) {
    float s, c;
    __sincosf(ang, &s, &c);
    float2 w = make_float2(c, s), cur = w;
    x[1] = cmulf(x[1], cur);
    #pragma unroll
    for (int k = 2; k < 8; ++k) { cur = cmulf(cur, w); x[k] = cmulf(x[k], cur); }
}

// ---------------- K1a ----------------
__global__ __launch_bounds__(256) void k1a_kernel(const float* __restrict__ v,
                                                  __half2* __restrict__ ybuf, int b0) {
    __shared__ float2 T[64 * 65];
    const int blk = blockIdx.x;
    const int ct = blk & 1;
    const int n2 = (blk >> 1) & 63;
    const int bl = blk >> 7;
    const int bat = b0 + bl;
    const int t = threadIdx.x;
    const int p = t & 63;
    const int g = t >> 6;

    const float* vb = v + ((size_t)bat << 20) + (size_t)n2 * CC + ct * 128 + 2 * p;
    float2 X[2][8];
    #pragma unroll
    for (int s = 0; s < 2; ++s) {
        const int bd = g + 4 * s;
        #pragma unroll
        for (int a = 0; a < 8; ++a)
            X[s][a] = *(const float2*)(vb + (size_t)(8 * a + bd) * 16384);
    }
    #pragma unroll
    for (int s = 0; s < 2; ++s) {
        const int bd = g + 4 * s;
        dif8<1>(X[s]);
        twid7(X[s], -PI2_64 * (float)bd);          // W64^{bd*k0}
        float2* row = T + p * 65;
        #pragma unroll
        for (int k0 = 0; k0 < 8; ++k0) row[bd + 8 * k0] = X[s][k0];
    }
    __syncthreads();

    __half2* yb = ybuf + (size_t)bl * (64 * 64 * 128) + ct * 64 + p;
    #pragma unroll
    for (int s = 0; s < 2; ++s) {
        const int k0 = g + 4 * s;
        float2 Y[8];
        const float2* row = T + p * 65 + 8 * k0;
        #pragma unroll
        for (int b = 0; b < 8; ++b) Y[b] = row[b];
        dif8<1>(Y);                                 // A[k0 + 8*k1b]
        float bs, bc, ss, sc;
        __sincosf(-PI2_4096 * (float)(n2 * k0), &bs, &bc);
        __sincosf(-PI2_512 * (float)n2, &ss, &sc);
        float2 cur = make_float2(bc, bs), stp = make_float2(sc, ss);
        #pragma unroll
        for (int k1b = 0; k1b < 8; ++k1b) {
            float2 r = cmulf(Y[k1b], cur);
            yb[(size_t)((k0 + 8 * k1b) * 64 + n2) * 128] = __floats2half2_rn(r.x, r.y);
            cur = cmulf(cur, stp);
        }
    }
}

// ---------------- K1b ----------------
__global__ __launch_bounds__(256) void k1b_kernel(const __half2* __restrict__ ybuf,
                                                  __half2* __restrict__ zbuf, int b0) {
    __shared__ float2 T[64 * 65];
    const int blk = blockIdx.x;
    const int ct = blk & 1;
    const int k1 = (blk >> 1) & 63;
    const int bl = blk >> 7;
    const int bat = b0 + bl;
    const int t = threadIdx.x;
    const int p = t & 63;
    const int g = t >> 6;
    const float R = 0.70710678118654752f;

    const __half2* yb = ybuf + (size_t)bl * (64 * 64 * 128) + (size_t)k1 * (64 * 128) + ct * 64 + p;
    float2 X[2][8];
    #pragma unroll
    for (int s = 0; s < 2; ++s) {
        const int bd = g + 4 * s;
        #pragma unroll
        for (int a = 0; a < 8; ++a)
            X[s][a] = __half22float2(yb[(size_t)(8 * a + bd) * 128]);
    }
    #pragma unroll
    for (int s = 0; s < 2; ++s) {
        const int bd = g + 4 * s;
        dif8<1>(X[s]);
        twid7(X[s], -PI2_64 * (float)bd);
        float2* row = T + p * 65;
        #pragma unroll
        for (int k0 = 0; k0 < 8; ++k0) row[bd + 8 * k0] = X[s][k0];
    }
    __syncthreads();

    __half2* zb = zbuf + ((size_t)(bat * 64 + k1) * 16) * 128 + ct * 64 + p;
    #pragma unroll
    for (int s = 0; s < 2; ++s) {
        const int k20 = g + 4 * s;
        float2 r[8];
        const float2* row = T + p * 65 + 8 * k20;
        #pragma unroll
        for (int b = 0; b < 8; ++b) r[b] = row[b];
        // B[k20] = sum r[b];  B[k20+56] = sum r[b]*e^{+i pi b/4}
        float2 sum0 = make_float2(0.f, 0.f);
        #pragma unroll
        for (int b = 0; b < 8; ++b) sum0 = cadd(sum0, r[b]);
        float2 e0 = csub(r[0], r[4]);
        float2 e1 = csub(r[1], r[5]);
        float2 e2 = csub(r[2], r[6]);
        float2 e3 = csub(r[3], r[7]);
        float2 sum7 = cadd(cadd(e0, cmulf(e1, make_float2(R, R))),
                           cadd(make_float2(-e2.y, e2.x), cmulf(e3, make_float2(-R, R))));
        zb[(size_t)k20 * 128]       = __floats2half2_rn(sum0.x, sum0.y);
        zb[(size_t)(k20 + 8) * 128] = __floats2half2_rn(sum7.x, sum7.y);
    }
}

// ---------------- K2: per-(mode, o-half) channel mix via MFMA ----------------
// X (64 rows = 32 Re + 32 Im batches, 256 channels) staged fp16 in LDS, row-major
// with XOR bank swizzle. R[m] fp32 read from global, split R = hi + lo (fp16 pair)
// -> 2 MFMAs per fragment, preserving fp32-R precision. 4 waves x (64x32) tiles.
__device__ __forceinline__ int swzh(int r, int col) {
    return r * 256 + (col ^ ((r & 7) << 3));       // half-index swizzle = byte ^ ((r&7)<<4)
}

__global__ __launch_bounds__(256) void k2_kernel(const __half2* __restrict__ zbuf,
                                                 const float* __restrict__ R,
                                                 __half* __restrict__ gre,
                                                 __half* __restrict__ gim) {
    __shared__ __align__(16) __half XT[64 * 256];   // [r][i] fp16, swizzled; r: 0..31 Re(b), 32..63 Im(b)
    const int mh = blockIdx.x & 1;
    const int m  = blockIdx.x >> 1;
    const int t = threadIdx.x;
    const int k1 = m & 63, k2 = m >> 6;
    int k1p, jp;
    if (k1 == 0) { k1p = 0;       jp = (k2 == 0) ? 0 : (16 - k2); }
    else         { k1p = 64 - k1; jp = 15 - k2; }
    {
        const int b  = t & 31;
        const int pg = t >> 5;
        const __half2* zm = zbuf + ((size_t)(b * 64 + k1 ) * 16 + k2) * 128;
        const __half2* zp = zbuf + ((size_t)(b * 64 + k1p) * 16 + jp) * 128;
        #pragma unroll
        for (int q = 0; q < 16; ++q) {
            int pp = pg + 8 * q;
            float2 a = __half22float2(zm[pp]);
            float2 c = __half22float2(zp[pp]);
            // Hermitian untangle of channel pair (2pp, 2pp+1):
            *(__half2*)&XT[swzh(b,      2 * pp)] = __floats2half2_rn(0.5f * (a.x + c.x), 0.5f * (a.y + c.y));
            *(__half2*)&XT[swzh(b + 32, 2 * pp)] = __floats2half2_rn(0.5f * (a.y - c.y), 0.5f * (c.x - a.x));
        }
    }
    __syncthreads();

    const int w  = t >> 6;         // wave -> 32-col slice
    const int l  = t & 63;
    const int lr = l & 15;         // A-row / B-col / D-col within tile
    const int kg = l >> 4;         // k-group (8 consecutive k per fragment)
    const int colbase = mh * 128 + w * 32;

    f32x4 acc[4][2];
    #pragma unroll
    for (int mt = 0; mt < 4; ++mt)
        #pragma unroll
        for (int nt = 0; nt < 2; ++nt)
            acc[mt][nt] = (f32x4){0.f, 0.f, 0.f, 0.f};

    const float* Rb = R + (size_t)m * 65536 + colbase + lr;

    for (int kt = 0; kt < 8; ++kt) {
        f16x8 afrag[4];
        #pragma unroll
        for (int mt = 0; mt < 4; ++mt)
            afrag[mt] = *(const f16x8*)&XT[swzh(mt * 16 + lr, kt * 32 + kg * 8)];
        #pragma unroll
        for (int nt = 0; nt < 2; ++nt) {
            const float* rp = Rb + (size_t)(kt * 32 + kg * 8) * 256 + nt * 16;
            float rv[8];
            #pragma unroll
            for (int j = 0; j < 8; ++j) rv[j] = rp[(size_t)j * 256];
            f16x8 bhi, blo;
            #pragma unroll
            for (int j = 0; j < 8; ++j) {
                _Float16 h = (_Float16)rv[j];
                bhi[j] = h;
                blo[j] = (_Float16)(rv[j] - (float)h);
            }
            #pragma unroll
            for (int mt = 0; mt < 4; ++mt) {
                acc[mt][nt] = __builtin_amdgcn_mfma_f32_16x16x32_f16(afrag[mt], bhi, acc[mt][nt], 0, 0, 0);
                acc[mt][nt] = __builtin_amdgcn_mfma_f32_16x16x32_f16(afrag[mt], blo, acc[mt][nt], 0, 0, 0);
            }
        }
    }

    // D layout: col = lane&15, row = (lane>>4)*4 + reg  [dtype-independent on gfx950]
    #pragma unroll
    for (int mt = 0; mt < 4; ++mt) {
        __half* plane = (mt < 2) ? gre : gim;      // rows 0..31 -> Re plane, 32..63 -> Im plane
        const int bb = (mt & 1) * 16 + kg * 4;
        #pragma unroll
        for (int nt = 0; nt < 2; ++nt) {
            const int n = colbase + nt * 16 + lr;
            #pragma unroll
            for (int j = 0; j < 4; ++j) {
                plane[((size_t)m * BB + (bb + j)) * CC + n] = __float2half_rn(acc[mt][nt][j]);
            }
        }
    }
}

// ---------------- K3a (no LDS) ----------------
__global__ __launch_bounds__(256) void k3a_kernel(const __half* __restrict__ gre,
                                                  const __half* __restrict__ gim,
                                                  __half2* __restrict__ tbuf, int b0) {
    const int blk = blockIdx.x;
    const int ct = blk & 1;
    const int k1 = (blk >> 1) & 63;
    const int bl = blk >> 7;
    const int bat = b0 + bl;
    const int t = threadIdx.x;
    const int p = t & 63;
    const int g = t >> 6;

    float2 Zd[8], Zc[8];
    #pragma unroll
    for (int k20 = 0; k20 < 8; ++k20) {
        int m = k1 + 64 * k20;
        size_t off = ((size_t)m * BB + bat) * CC + ct * 128 + 2 * p;
        float2 a = __half22float2(*(const __half2*)(gre + off));
        float2 c = __half22float2(*(const __half2*)(gim + off));
        Zd[k20] = make_float2(a.x - c.y, c.x + a.y);
        int mp = 512 - k1 - 64 * k20;
        if (mp != 512) {
            size_t offp = ((size_t)mp * BB + bat) * CC + ct * 128 + 2 * p;
            float2 ap = __half22float2(*(const __half2*)(gre + offp));
            float2 cp = __half22float2(*(const __half2*)(gim + offp));
            Zc[k20] = make_float2(ap.x + cp.y, ap.y - cp.x);
        } else {
            Zc[k20] = make_float2(0.f, 0.f);
        }
    }

    __half2* tb = tbuf + (size_t)bl * (64 * 64 * 128) + (size_t)k1 * 128 + ct * 64 + p;
    #pragma unroll
    for (int s = 0; s < 2; ++s) {
        const int bd = g + 4 * s;
        float w8s, w8c;
        __sincosf(-PI_4 * (float)bd, &w8s, &w8c);   // e^{-i pi bd/4}
        float2 u[8];
        #pragma unroll
        for (int k20 = 0; k20 < 8; ++k20)
            u[k20] = cadd(Zd[k20], cmulf(Zc[k20], make_float2(w8c, w8s)));
        twid7(u, PI2_64 * (float)bd);               // e^{+i 2pi bd k20/64}
        dif8<-1>(u);                                // t[8a+bd] at index a
        float bs, bc, ss, sc;
        __sincosf(PI2_4096 * (float)(bd * k1), &bs, &bc);
        __sincosf(PI2_512 * (float)k1, &ss, &sc);
        float2 cur = make_float2(bc, bs), stp = make_float2(sc, ss);
        #pragma unroll
        for (int a = 0; a < 8; ++a) {
            float2 r = cmulf(u[a], cur);
            tb[(size_t)(8 * a + bd) * (64 * 128)] = __floats2half2_rn(r.x, r.y);
            cur = cmulf(cur, stp);
        }
    }
}

// ---------------- K3b ----------------
__global__ __launch_bounds__(256) void k3b_kernel(const __half2* __restrict__ tbuf,
                                                  const float* __restrict__ v,
                                                  float* __restrict__ out, int b0) {
    __shared__ float2 T[64 * 65];
    const int blk = blockIdx.x;
    const int ct = blk & 1;
    const int n2 = (blk >> 1) & 63;
    const int bl = blk >> 7;
    const int bat = b0 + bl;
    const int t = threadIdx.x;
    const int p = t & 63;
    const int g = t >> 6;

    const __half2* tb = tbuf + (size_t)bl * (64 * 64 * 128) + (size_t)n2 * (64 * 128) + ct * 64 + p;
    float2 X[2][8];
    #pragma unroll
    for (int s = 0; s < 2; ++s) {
        const int be = g + 4 * s;
        #pragma unroll
        for (int a = 0; a < 8; ++a)
            X[s][a] = __half22float2(tb[(size_t)(8 * a + be) * 128]);
    }
    #pragma unroll
    for (int s = 0; s < 2; ++s) {
        const int be = g + 4 * s;
        dif8<-1>(X[s]);
        twid7(X[s], PI2_64 * (float)be);            // e^{+i 2pi be j0/64}
        float2* row = T + p * 65;
        #pragma unroll
        for (int j0 = 0; j0 < 8; ++j0) row[be + 8 * j0] = X[s][j0];
    }
    __syncthreads();

    const float sc = 1.0f / 4096.0f;
    const float* vb = v   + ((size_t)bat << 20) + (size_t)n2 * CC + ct * 128 + 2 * p;
    float*       ob = out + ((size_t)bat << 20) + (size_t)n2 * CC + ct * 128 + 2 * p;
    #pragma unroll
    for (int s = 0; s < 2; ++s) {
        const int j0 = g + 4 * s;
        float2 r[8];
        const float2* row = T + p * 65 + 8 * j0;
        #pragma unroll
        for (int b = 0; b < 8; ++b) r[b] = row[b];
        dif8<-1>(r);                                // x[j0 + 8*j1] at index j1
        #pragma unroll
        for (int j1 = 0; j1 < 8; ++j1) {
            int n1 = j0 + 8 * j1;
            size_t off = (size_t)n1 * 16384;
            float2 vz = *(const float2*)(vb + off);
            float2 o = make_float2(vz.x + r[j1].x * sc, vz.y + r[j1].y * sc);
            *(float2*)(ob + off) = o;
        }
    }
}

extern "C" void kernel_launch(void* const* d_in, const int* in_sizes, int n_in,
                              void* d_out, int out_size, void* d_ws, size_t ws_size,
                              hipStream_t stream) {
    const float* v = (const float*)d_in[0];
    const float* R = (const float*)d_in[1];
    float* out = (float*)d_out;

    __half2* ybuf = (__half2*)d_ws;                               // 16*64*64*128 h2 = 33.5 MB (also tbuf)
    __half2* zbuf = ybuf + (size_t)16 * 64 * 64 * 128;            // 32*64*16*128 h2 = 16.8 MB
    __half*  gre  = (__half*)(zbuf + (size_t)32 * 64 * 16 * 128); // 8.4 MB
    __half*  gim  = gre + (size_t)MM * BB * CC;                   // 8.4 MB (total 64 MiB)

    for (int h = 0; h < 2; ++h) {
        k1a_kernel<<<2048, 256, 0, stream>>>(v, ybuf, h * 16);
        k1b_kernel<<<2048, 256, 0, stream>>>(ybuf, zbuf, h * 16);
    }
    k2_kernel<<<1024, 256, 0, stream>>>(zbuf, R, gre, gim);
    for (int h = 0; h < 2; ++h) {
        k3a_kernel<<<2048, 256, 0, stream>>>(gre, gim, ybuf, h * 16);
        k3b_kernel<<<2048, 256, 0, stream>>>(ybuf, v, out, h * 16);
    }
}